// Round 11
// baseline (3012.158 us; speedup 1.0000x reference)
//
#include <hip/hip_runtime.h>
#include <hip/hip_bf16.h>

using bf16 = __hip_bfloat16;
typedef __attribute__((ext_vector_type(8))) short short8;   // 8 bf16 (MFMA A/B frag)
typedef __attribute__((ext_vector_type(4))) float f32x4;    // MFMA C/D frag

#define MFMA16(A, B, C) __builtin_amdgcn_mfma_f32_16x16x32_bf16(A, B, C, 0, 0, 0)

constexpr int Mdim = 512;
constexpr int Ddim = 1024;
constexpr int Hdim = 2048;
constexpr size_t MH = (size_t)Mdim * Hdim;   // 512*2048 (H-space activations)

constexpr double Hs = 1.0 / 16.0;
// CF[s-1][j]: coefficient (times h) of K_{j+1} in the combination after stage s.
// Row 5 = 5th-order solution weights (also the G-accumulation weights).
constexpr float CF[6][6] = {
    {float(Hs * 1 / 5.), 0.f, 0.f, 0.f, 0.f, 0.f},
    {float(Hs * 3 / 40.), float(Hs * 9 / 40.), 0.f, 0.f, 0.f, 0.f},
    {float(Hs * 44 / 45.), float(-Hs * 56 / 15.), float(Hs * 32 / 9.), 0.f, 0.f, 0.f},
    {float(Hs * 19372 / 6561.), float(-Hs * 25360 / 2187.), float(Hs * 64448 / 6561.),
     float(-Hs * 212 / 729.), 0.f, 0.f},
    {float(Hs * 9017 / 3168.), float(-Hs * 355 / 33.), float(Hs * 46732 / 5247.),
     float(Hs * 49 / 176.), float(-Hs * 5103 / 18656.), 0.f},
    {float(Hs * 35 / 384.), 0.f, float(Hs * 500 / 1113.), float(Hs * 125 / 192.),
     float(-Hs * 2187 / 6784.), float(Hs * 11 / 84.)},
};

__device__ __forceinline__ float tanh_fast(float x) {
  float xc = fminf(fmaxf(x, -15.0f), 15.0f);
  float t = __expf(2.0f * xc);
  return (t - 1.0f) * __builtin_amdgcn_rcpf(t + 1.0f);
}

__device__ __forceinline__ void gload_lds16(const void* g, void* lds) {
  __builtin_amdgcn_global_load_lds((const __attribute__((address_space(1))) void*)g,
                                   (__attribute__((address_space(3))) void*)lds, 16, 0, 0);
}

enum { M_PLAIN = 0, M_INIT = 1, M_STG = 2, M_FINAL = 3 };

struct GArgs {
  const bf16* A;      // [M][KDIM] bf16 row-major
  const bf16* Bt;     // [NDIM][KDIM] bf16 row-major (B transposed)
  const float* b1;    // bias for tanh input [NDIM]
  const float* b2w1;  // b2@W1 [2048]
  const float* xin;   // x f32 (FINAL)
  const float* b2;    // b2 (FINAL)
  float* yW1;         // [512][2048] f32 running H-space state
  bf16* T;            // [512][2048] bf16 tanh output (next GEMM's A)
  bf16* K;            // 5 x [512][2048] bf16 K_j storage
  float* G;           // [512][2048] f32 accumulated CF5-weighted tanh
  bf16* Wout;         // PLAIN bf16 output (W21t)
  float* y;           // FINAL f32 output
  float* part;        // split-K partials: 128 tiles x 2 halves x 8192 f32 (8 MB)
  int* tkt;           // 128 tickets (zeroed per launch; finisher self-resets)
};

// Shared M_STG epilogue: given final C value cvv at (r, c), do RK stage math.
template <int STAGE>
__device__ __forceinline__ void stage_epilogue(const GArgs& a, float cvv, int r, int c) {
  const size_t idx = (size_t)r * Hdim + c;
  const float Kv = cvv + a.b2w1[c];
  if constexpr (STAGE <= 5) a.K[(size_t)(STAGE - 1) * MH + idx] = __float2bfloat16(Kv);
  float comb = a.yW1[idx] + CF[STAGE - 1][STAGE - 1] * Kv;
  if constexpr (STAGE > 1 && CF[STAGE - 1][0] != 0.f)
    comb += CF[STAGE - 1][0] * __bfloat162float(a.K[0 * MH + idx]);
  if constexpr (STAGE > 2 && CF[STAGE - 1][1] != 0.f)
    comb += CF[STAGE - 1][1] * __bfloat162float(a.K[1 * MH + idx]);
  if constexpr (STAGE > 3 && CF[STAGE - 1][2] != 0.f)
    comb += CF[STAGE - 1][2] * __bfloat162float(a.K[2 * MH + idx]);
  if constexpr (STAGE > 4 && CF[STAGE - 1][3] != 0.f)
    comb += CF[STAGE - 1][3] * __bfloat162float(a.K[3 * MH + idx]);
  if constexpr (STAGE > 5 && CF[STAGE - 1][4] != 0.f)
    comb += CF[STAGE - 1][4] * __bfloat162float(a.K[4 * MH + idx]);
  if constexpr (STAGE < 6) {
    const float tv = tanh_fast(comb + a.b1[c]);
    a.T[idx] = __float2bfloat16(tv);
    if constexpr (CF[5][STAGE] != 0.f) a.G[idx] += CF[5][STAGE] * tv;
  } else {
    a.yW1[idx] = comb;                       // 5th-order yW1 update
    const float tv = tanh_fast(comb + a.b1[c]);
    a.T[idx] = __float2bfloat16(tv);         // T_1 of next step
    a.G[idx] += CF[5][0] * tv;
  }
}

// ===== Hot stage kernel: C = T(512x2048) @ W21t^T ; 64x128 block tile, split-K x2 =====
// Grid 256: xcd=bid&7; idx=bid>>3; nt=xcd*2+(idx&1); kh=(idx>>1)&1; mt=idx>>2.
// 8 waves = 4(kq, K-quarter of BK) x 2(nh, 64-col half); wave tile 64x64 (16 MFMA/iter,
// 8 ds_read_b128) -> each staged byte read once (A by 2 nh... A 1x per nh pair? A read
// by both nh waves of same kq? No: af spans all 64 rows; A read 2x (nh), B 1x -> reads
// 64KB vs staged 48KB/iter, 30% less LDS/FLOP than 64x32 waves). 3x48KB buffers,
// counted vmcnt(6) (6 loads/thread/tile, distance 2). In-block 4-way K-reduce via LDS
// owner-distribution (128KB, aliases buffers). Cross-block: both halves store 32KB f32
// partial + threadfence + ticket atomicAdd; LAST arriver (wait-free, no co-residency
// assumption) acquires, sums both, runs epilogue on all 512 threads, resets ticket
// (safe: stream serialization orders next dispatch after this kernel fully ends).
template <int STAGE>
__global__ __launch_bounds__(512, 2) void fused_stage(GArgs a) {
  constexpr int NITER = 8;            // K-half 1024 / BK 128
  extern __shared__ char smem_c[];    // 3 x 49152 staging; reduce slots alias [0,128K)

  const int tid = threadIdx.x;
  const int lane = tid & 63;
  const int wid = tid >> 6;
  const int kq = wid & 3;
  const int nh = wid >> 2;
  const int fr = lane & 15;
  const int kg = (lane >> 4) & 3;

  const int bid = blockIdx.x;
  const int idx = bid >> 3;
  const int nt = (bid & 7) * 2 + (idx & 1);
  const int kh = (idx >> 1) & 1;
  const int mt = idx >> 2;
  const int brow = mt * 64, bcol = nt * 128;

  // staging: A 64x128 (2 passes), B 128x128 (4 passes); 16B chunks, source-side XOR.
  const int rs0 = tid >> 4;                  // 0..31
  const int cg = (tid & 15) ^ (rs0 & 7);     // (rs0+32p)&7 == rs0&7
  const bf16* pA0 = a.A + ((size_t)(brow + rs0) << 11) + kh * 1024 + cg * 8;
  const bf16* pA1 = pA0 + ((size_t)32 << 11);
  const bf16* pB0 = a.Bt + ((size_t)(bcol + rs0) << 11) + kh * 1024 + cg * 8;
  const bf16* pB1 = pB0 + ((size_t)32 << 11);
  const bf16* pB2 = pB0 + ((size_t)64 << 11);
  const bf16* pB3 = pB0 + ((size_t)96 << 11);
  char* dA = smem_c + tid * 16;              // linear LDS dest (gload constraint)
  char* dB = smem_c + 16384 + tid * 16;

#define STG(T_)                                                                   \
  {                                                                               \
    constexpr int B_ = ((T_) % 3) * 49152;                                        \
    constexpr int KO_ = (T_)*128;                                                 \
    gload_lds16(pA0 + KO_, dA + B_);         gload_lds16(pA1 + KO_, dA + B_ + 8192); \
    gload_lds16(pB0 + KO_, dB + B_);         gload_lds16(pB1 + KO_, dB + B_ + 8192); \
    gload_lds16(pB2 + KO_, dB + B_ + 16384); gload_lds16(pB3 + KO_, dB + B_ + 24576); \
  }

  // ds_read bases: A row r at r*256 within A region; B row at 16384 + r*256.
  const int xc = (((kq * 4 + kg) ^ (fr & 7)) << 4);
  const char* rA = smem_c + fr * 256 + xc;                     // + mf*4096 + buf
  const char* rB = smem_c + 16384 + (nh * 64 + fr) * 256 + xc; // + nf*4096 + buf

  f32x4 acc[4][4] = {};
  STG(0) STG(1)

#pragma unroll
  for (int t = 0; t < NITER; ++t) {
    if (t < NITER - 1) asm volatile("s_waitcnt vmcnt(6)" ::: "memory");
    else               asm volatile("s_waitcnt vmcnt(0)" ::: "memory");
    __builtin_amdgcn_s_barrier();
    __builtin_amdgcn_sched_barrier(0);
    switch (t + 2) {   // compile-time staged prefetch (loop is fully unrolled)
      case 2: STG(2) break; case 3: STG(3) break; case 4: STG(4) break;
      case 5: STG(5) break; case 6: STG(6) break; case 7: STG(7) break;
      default: break;
    }
    const int BO = (t % 3) * 49152;
    short8 af[4], bw[4];
    af[0] = *(const short8*)(rA + BO);
    af[1] = *(const short8*)(rA + BO + 4096);
    af[2] = *(const short8*)(rA + BO + 8192);
    af[3] = *(const short8*)(rA + BO + 12288);
    bw[0] = *(const short8*)(rB + BO);
    bw[1] = *(const short8*)(rB + BO + 4096);
    bw[2] = *(const short8*)(rB + BO + 8192);
    bw[3] = *(const short8*)(rB + BO + 12288);
    __builtin_amdgcn_s_setprio(1);
#pragma unroll
    for (int mf = 0; mf < 4; ++mf)
#pragma unroll
      for (int nf = 0; nf < 4; ++nf) acc[mf][nf] = MFMA16(af[mf], bw[nf], acc[mf][nf]);
    __builtin_amdgcn_s_setprio(0);
  }
#undef STG

  // ---- in-block 4-way K-reduce: 32 positions x 4 kq x 1KB slots (aliases buffers) ----
  __syncthreads();
#pragma unroll
  for (int mf = 0; mf < 4; ++mf)
#pragma unroll
    for (int nf = 0; nf < 4; ++nf)
      *(f32x4*)(smem_c + (((mf * 8 + nh * 4 + nf) * 4 + kq) << 10) + lane * 16) = acc[mf][nf];
  __syncthreads();

  f32x4 sum[4];
#pragma unroll
  for (int of = 0; of < 4; ++of) {
    const int p = wid * 4 + of;        // owned position 0..31
    f32x4 s = {};
#pragma unroll
    for (int k = 0; k < 4; ++k)
      s += *(const f32x4*)(smem_c + (((p * 4 + k) << 10)) + lane * 16);
    sum[of] = s;
  }

  // ---- cross-block split-K: last arriver finishes ----
  const int tile = mt * 16 + nt;
  float* own = a.part + ((size_t)(tile * 2 + kh)) * 8192;
  float* other = a.part + ((size_t)(tile * 2 + (1 - kh))) * 8192;
  int* flg = a.tkt + tile;
#pragma unroll
  for (int of = 0; of < 4; ++of)
    *(f32x4*)(own + (wid * 4 + of) * 256 + lane * 4) = sum[of];
  __syncthreads();                     // drains stores (hipcc vmcnt(0) before barrier)
  int* sh = (int*)(smem_c + 131072);
  if (tid == 0) {
    __threadfence();                   // L2 writeback: partial visible agent-wide
    int old = atomicAdd(flg, 1);       // device-scope coherence point
    if (old == 1) {
      __threadfence();                 // invalidate: see partner's partial
      atomicExch(flg, 0);              // self-reset for next dispatch (stream-ordered)
    }
    *sh = old;
  }
  __syncthreads();
  if (*sh == 0) return;                // partner (last arriver) will finish this tile

#pragma unroll
  for (int of = 0; of < 4; ++of)
    sum[of] += *(const f32x4*)(other + (wid * 4 + of) * 256 + lane * 4);

  // ---- epilogue on all 512 threads; C/D layout (m89): col=lane&15, row=(lane>>4)*4+e
#pragma unroll
  for (int of = 0; of < 4; ++of) {
    const int p = wid * 4 + of;
    const int mfo = p >> 3, nfr = p & 7;
    const int c = bcol + nfr * 16 + fr;
    const int r0 = brow + mfo * 16 + kg * 4;
#pragma unroll
    for (int e = 0; e < 4; ++e) stage_epilogue<STAGE>(a, sum[of][e], r0 + e, c);
  }
}

// ===== Setup / init / final kernel (round-10 proven structure, unchanged) =====
template <int MODE, int STAGE, int NDIM, int KDIM>
__global__ __launch_bounds__(512, 2) void fused_gemm(GArgs a) {
  constexpr int BK = 128;
  constexpr int NITER = KDIM / BK;
  constexpr int NP = (NDIM / 64) / 8;

  extern __shared__ char smem_c[];  // 98304 = 3 x (A 16KB | B 16KB)

  const int tid = threadIdx.x;
  const int lane = tid & 63;
  const int wid = tid >> 6;
  const int kq = wid & 3;
  const int nh = wid >> 2;
  const int fr = lane & 15;
  const int kg = (lane >> 4) & 3;

  const int bid = blockIdx.x;
  const int nt = (bid & 7) * NP + ((bid >> 3) % NP);
  const int mt = (bid >> 3) / NP;
  const int brow = mt * 64, bcol = nt * 64;

  const int rs0 = tid >> 4;
  const int cgS = (tid & 15) ^ (rs0 & 7);
  const bf16* pA0 = a.A + (size_t)(brow + rs0) * KDIM + cgS * 8;
  const bf16* pA1 = pA0 + (size_t)32 * KDIM;
  const bf16* pB0 = a.Bt + (size_t)(bcol + rs0) * KDIM + cgS * 8;
  const bf16* pB1 = pB0 + (size_t)32 * KDIM;
  char* dA = smem_c + tid * 16;
  char* dB = smem_c + 16384 + tid * 16;

#define STAGE_TILE(T_)                                                       \
  {                                                                          \
    const int B_ = ((T_) % 3) * 32768;                                       \
    const int KO_ = (T_)*BK;                                                 \
    gload_lds16(pA0 + KO_, dA + B_); gload_lds16(pA1 + KO_, dA + B_ + 8192); \
    gload_lds16(pB0 + KO_, dB + B_); gload_lds16(pB1 + KO_, dB + B_ + 8192); \
  }

  const int xA = (((kq * 4 + kg) ^ (fr & 7)) << 4);
  const char* rA = smem_c + fr * 256 + xA;
  const char* rB = smem_c + 16384 + (nh * 32 + fr) * 256 + xA;

  f32x4 acc[4][2] = {};

  STAGE_TILE(0)
  STAGE_TILE(1)

#pragma unroll
  for (int t = 0; t < NITER; ++t) {
    if (t < NITER - 1) asm volatile("s_waitcnt vmcnt(4)" ::: "memory");
    else               asm volatile("s_waitcnt vmcnt(0)" ::: "memory");
    __builtin_amdgcn_s_barrier();
    __builtin_amdgcn_sched_barrier(0);
    if (t + 2 < NITER) STAGE_TILE(t + 2)
    const int BO = (t % 3) * 32768;
    short8 af[4], bw[2];
    af[0] = *(const short8*)(rA + BO);
    af[1] = *(const short8*)(rA + BO + 4096);
    af[2] = *(const short8*)(rA + BO + 8192);
    af[3] = *(const short8*)(rA + BO + 12288);
    bw[0] = *(const short8*)(rB + BO);
    bw[1] = *(const short8*)(rB + BO + 4096);
    __builtin_amdgcn_s_setprio(1);
#pragma unroll
    for (int mf = 0; mf < 4; ++mf)
#pragma unroll
      for (int nf = 0; nf < 2; ++nf) acc[mf][nf] = MFMA16(af[mf], bw[nf], acc[mf][nf]);
    __builtin_amdgcn_s_setprio(0);
  }
#undef STAGE_TILE

  __syncthreads();
#pragma unroll
  for (int mf = 0; mf < 4; ++mf)
#pragma unroll
    for (int nf = 0; nf < 2; ++nf)
      *(f32x4*)(smem_c + (((mf * 4 + nh * 2 + nf) * 4 + kq) << 10) + lane * 16) = acc[mf][nf];
  __syncthreads();

#pragma unroll
  for (int of = 0; of < 2; ++of) {
    const int p = wid * 2 + of;
    const int mfo = p >> 2, nfo = p & 3;
    f32x4 s = {};
#pragma unroll
    for (int k = 0; k < 4; ++k)
      s += *(const f32x4*)(smem_c + (((p * 4 + k) << 10)) + lane * 16);

    const int c = bcol + nfo * 16 + fr;
    const int r0 = brow + mfo * 16 + kg * 4;
#pragma unroll
    for (int e = 0; e < 4; ++e) {
      const int r = r0 + e;
      const size_t idx = (size_t)r * NDIM + c;
      const float cvv = s[e];
      if constexpr (MODE == M_PLAIN) {
        a.Wout[idx] = __float2bfloat16(cvv);
      } else if constexpr (MODE == M_INIT) {
        a.yW1[idx] = cvv;
        const float tv = tanh_fast(cvv + a.b1[c]);
        a.T[idx] = __float2bfloat16(tv);
        a.G[idx] = CF[5][0] * tv;
      } else {  // M_FINAL
        a.y[idx] = a.xin[idx] + cvv + a.b2[c];
      }
    }
  }
}

// fp32 [R][C] -> bf16 [C][R]
__global__ void transpose_to_bf16(const float* __restrict__ in, bf16* __restrict__ out, int R,
                                  int C) {
  __shared__ float t[32][33];
  const int c0 = blockIdx.x * 32, r0 = blockIdx.y * 32;
#pragma unroll
  for (int i = threadIdx.y; i < 32; i += 8)
    t[i][threadIdx.x] = in[(size_t)(r0 + i) * C + c0 + threadIdx.x];
  __syncthreads();
#pragma unroll
  for (int i = threadIdx.y; i < 32; i += 8)
    out[(size_t)(c0 + i) * R + r0 + threadIdx.x] = __float2bfloat16(t[threadIdx.x][i]);
}

// fp32 -> bf16 elementwise (4 per thread)
__global__ void cast_bf16(const float* __restrict__ in, bf16* __restrict__ out, int n4) {
  int i = blockIdx.x * 256 + threadIdx.x;
  if (i < n4) {
    float4 v = *(const float4*)(in + i * 4);
    bf16* o = out + i * 4;
    o[0] = __float2bfloat16(v.x); o[1] = __float2bfloat16(v.y);
    o[2] = __float2bfloat16(v.z); o[3] = __float2bfloat16(v.w);
  }
}

// b2w1[h'] = sum_d b2[d] * W1[d][h']   (W1 f32 [1024][2048])
__global__ void b2w1_kernel(const float* __restrict__ b2, const float* __restrict__ W1,
                            float* __restrict__ out) {
  const int h = blockIdx.x * 256 + threadIdx.x;
  float s = 0.f;
  for (int d = 0; d < Ddim; ++d) s += b2[d] * W1[(size_t)d * Hdim + h];
  out[h] = s;
}

extern "C" void kernel_launch(void* const* d_in, const int* in_sizes, int n_in, void* d_out,
                              int out_size, void* d_ws, size_t ws_size, hipStream_t stream) {
  const float* x = (const float*)d_in[0];
  const float* W1 = (const float*)d_in[1];
  const float* b1 = (const float*)d_in[2];
  const float* W2 = (const float*)d_in[3];
  const float* b2 = (const float*)d_in[4];
  float* y = (float*)d_out;

  char* ws = (char*)d_ws;
  bf16* W1t = (bf16*)(ws + 0);                  // [2048][1024] bf16, 4 MB   (W1^T)
  bf16* W2bf = (bf16*)(ws + (4ull << 20));      // [2048][1024] bf16, 4 MB   (W2 rm)
  bf16* W2t = (bf16*)(ws + (8ull << 20));       // [1024][2048] bf16, 4 MB   (W2^T)
  bf16* W21t = (bf16*)(ws + (12ull << 20));     // [2048][2048] bf16, 8 MB   ((W2@W1)^T)
  bf16* xbf = (bf16*)(ws + (20ull << 20));      // [512][1024] bf16, 1 MB
  bf16* Tbuf = (bf16*)(ws + (21ull << 20));     // [512][2048] bf16, 2 MB
  bf16* Kbuf = (bf16*)(ws + (23ull << 20));     // 5 x [512][2048] bf16, 10 MB
  bf16* Gbf = (bf16*)(ws + (33ull << 20));      // [512][2048] bf16, 2 MB
  float* yW1 = (float*)(ws + (35ull << 20));    // [512][2048] f32, 4 MB
  float* Gacc = (float*)(ws + (39ull << 20));   // [512][2048] f32, 4 MB
  float* b2w1 = (float*)(ws + (43ull << 20));   // [2048] f32 (8 KB)
  int* tkt = (int*)(ws + (43ull << 20) + 16384);  // 128 ints
  float* part = (float*)(ws + (44ull << 20));   // 128 x 2 x 8192 f32, 8 MB (44..52)

  GArgs a = {};
  a.b1 = b1; a.b2w1 = b2w1; a.xin = x; a.b2 = b2;
  a.yW1 = yW1; a.T = Tbuf; a.K = Kbuf; a.G = Gacc; a.y = y;
  a.part = part; a.tkt = tkt;

  constexpr int SMEM = 98304;
  constexpr int SMEM_STG = 147456;
  hipFuncSetAttribute((const void*)&fused_gemm<M_PLAIN, 0, Hdim, 1024>,
                      hipFuncAttributeMaxDynamicSharedMemorySize, SMEM);
  hipFuncSetAttribute((const void*)&fused_gemm<M_INIT, 0, Hdim, 1024>,
                      hipFuncAttributeMaxDynamicSharedMemorySize, SMEM);
  hipFuncSetAttribute((const void*)&fused_gemm<M_FINAL, 0, Ddim, Hdim>,
                      hipFuncAttributeMaxDynamicSharedMemorySize, SMEM);
  hipFuncSetAttribute((const void*)&fused_stage<1>, hipFuncAttributeMaxDynamicSharedMemorySize,
                      SMEM_STG);
  hipFuncSetAttribute((const void*)&fused_stage<2>, hipFuncAttributeMaxDynamicSharedMemorySize,
                      SMEM_STG);
  hipFuncSetAttribute((const void*)&fused_stage<3>, hipFuncAttributeMaxDynamicSharedMemorySize,
                      SMEM_STG);
  hipFuncSetAttribute((const void*)&fused_stage<4>, hipFuncAttributeMaxDynamicSharedMemorySize,
                      SMEM_STG);
  hipFuncSetAttribute((const void*)&fused_stage<5>, hipFuncAttributeMaxDynamicSharedMemorySize,
                      SMEM_STG);
  hipFuncSetAttribute((const void*)&fused_stage<6>, hipFuncAttributeMaxDynamicSharedMemorySize,
                      SMEM_STG);

  // ---- setup (one-time per launch) ----
  hipMemsetAsync(tkt, 0, 1024, stream);   // tickets start 0 (finishers self-reset)
  transpose_to_bf16<<<dim3(Hdim / 32, Ddim / 32), dim3(32, 8), 0, stream>>>(W1, W1t, Ddim, Hdim);
  transpose_to_bf16<<<dim3(Ddim / 32, Hdim / 32), dim3(32, 8), 0, stream>>>(W2, W2t, Hdim, Ddim);
  cast_bf16<<<(Hdim * Ddim / 4 + 255) / 256, 256, 0, stream>>>(W2, W2bf, Hdim * Ddim / 4);
  cast_bf16<<<(Mdim * Ddim / 4 + 255) / 256, 256, 0, stream>>>(x, xbf, Mdim * Ddim / 4);
  b2w1_kernel<<<Hdim / 256, 256, 0, stream>>>(b2, W1, b2w1);

  // W21t[h'][h] = sum_d W1[d,h']*W2[h,d]  : A=W1t [2048][1024], Bt=W2bf [2048][1024]
  {
    GArgs p = a; p.A = W1t; p.Bt = W2bf; p.Wout = W21t;
    fused_gemm<M_PLAIN, 0, Hdim, 1024><<<32 * 32, 512, SMEM, stream>>>(p);
  }
  // init: yW1 = x@W1 ; T1 = tanh(yW1+b1) ; G = CF5[0]*tanh
  {
    GArgs p = a; p.A = xbf; p.Bt = W1t;
    fused_gemm<M_INIT, 0, Hdim, 1024><<<8 * 32, 512, SMEM, stream>>>(p);
  }

  // ---- 16 RK steps, one H-space GEMM per stage (skip last step's stage 6) ----
  GArgs sg = a; sg.A = Tbuf; sg.Bt = W21t;
  for (int step = 0; step < 16; ++step) {
    fused_stage<1><<<256, 512, SMEM_STG, stream>>>(sg);
    fused_stage<2><<<256, 512, SMEM_STG, stream>>>(sg);
    fused_stage<3><<<256, 512, SMEM_STG, stream>>>(sg);
    fused_stage<4><<<256, 512, SMEM_STG, stream>>>(sg);
    fused_stage<5><<<256, 512, SMEM_STG, stream>>>(sg);
    if (step < 15)
      fused_stage<6><<<256, 512, SMEM_STG, stream>>>(sg);
  }

  // ---- final: y = x + Gbf@W2 + b2 ----
  cast_bf16<<<(int)(MH / 4 + 255) / 256, 256, 0, stream>>>(Gacc, Gbf, (int)(MH / 4));
  {
    GArgs p = a; p.A = Gbf; p.Bt = W2t;
    fused_gemm<M_FINAL, 0, Ddim, Hdim><<<8 * 16, 512, SMEM, stream>>>(p);
  }
}

// Round 12
// 1379.815 us; speedup vs baseline: 2.1830x; 2.1830x over previous
//
#include <hip/hip_runtime.h>
#include <hip/hip_bf16.h>

using bf16 = __hip_bfloat16;
typedef __attribute__((ext_vector_type(8))) short short8;   // 8 bf16 (MFMA A/B frag)
typedef __attribute__((ext_vector_type(4))) float f32x4;    // MFMA C/D frag
typedef __attribute__((ext_vector_type(4))) unsigned short u16x4;  // 4 bf16 chunk

#define MFMA16(A, B, C) __builtin_amdgcn_mfma_f32_16x16x32_bf16(A, B, C, 0, 0, 0)

constexpr int Mdim = 512;
constexpr int Ddim = 1024;
constexpr int Hdim = 2048;
constexpr size_t MH = (size_t)Mdim * Hdim;   // 512*2048 (H-space activations)
constexpr size_t KPLANE = MH / 4;            // owner-layout chunks per K stage plane

constexpr double Hs = 1.0 / 16.0;
// CF[s-1][j]: coefficient (times h) of K_{j+1} in the combination after stage s.
// Row 5 = 5th-order solution weights (also the G-accumulation weights).
constexpr float CF[6][6] = {
    {float(Hs * 1 / 5.), 0.f, 0.f, 0.f, 0.f, 0.f},
    {float(Hs * 3 / 40.), float(Hs * 9 / 40.), 0.f, 0.f, 0.f, 0.f},
    {float(Hs * 44 / 45.), float(-Hs * 56 / 15.), float(Hs * 32 / 9.), 0.f, 0.f, 0.f},
    {float(Hs * 19372 / 6561.), float(-Hs * 25360 / 2187.), float(Hs * 64448 / 6561.),
     float(-Hs * 212 / 729.), 0.f, 0.f},
    {float(Hs * 9017 / 3168.), float(-Hs * 355 / 33.), float(Hs * 46732 / 5247.),
     float(Hs * 49 / 176.), float(-Hs * 5103 / 18656.), 0.f},
    {float(Hs * 35 / 384.), 0.f, float(Hs * 500 / 1113.), float(Hs * 125 / 192.),
     float(-Hs * 2187 / 6784.), float(Hs * 11 / 84.)},
};

__device__ __forceinline__ float tanh_fast(float x) {
  float xc = fminf(fmaxf(x, -15.0f), 15.0f);
  float t = __expf(2.0f * xc);
  return (t - 1.0f) * __builtin_amdgcn_rcpf(t + 1.0f);
}

__device__ __forceinline__ unsigned short f2bf(float x) {
  bf16 b = __float2bfloat16(x);
  return *(unsigned short*)&b;
}
__device__ __forceinline__ float bf2f(unsigned short u) {
  bf16 b = *(bf16*)&u;
  return __bfloat162float(b);
}

__device__ __forceinline__ void gload_lds16(const void* g, void* lds) {
  __builtin_amdgcn_global_load_lds((const __attribute__((address_space(1))) void*)g,
                                   (__attribute__((address_space(3))) void*)lds, 16, 0, 0);
}

enum { M_PLAIN = 0, M_INIT = 1, M_STG = 2, M_FINAL = 3 };

struct GArgs {
  const bf16* A;      // [M][KDIM] bf16 row-major
  const bf16* Bt;     // [NDIM][KDIM] bf16 row-major (B transposed)
  const float* b1;    // bias for tanh input [NDIM]
  const float* b2w1;  // b2@W1 [2048]
  const float* xin;   // x f32 (FINAL)
  const float* b2;    // b2 (FINAL)
  float* yW1;         // [512][2048] f32 running H-space state (row-major)
  bf16* T;            // [512][2048] bf16 tanh output, row-major (next GEMM's A)
  bf16* K;            // 5 x MH bf16 K_j storage in OWNER layout (see epilogue)
  float* G;           // [512][2048] f32 accumulated CF5-weighted tanh (row-major)
  bf16* Wout;         // PLAIN bf16 output (W21t)
  float* y;           // FINAL f32 output
};

// C = A(M x KDIM) * Bt^T; 64x64 block tile; 8 waves = 4(K-quarter) x 2(N-half);
// wave tile 64x32 on a disjoint K=32 slice. BK=128, THREE 32KB buffers, prefetch
// distance 2, counted vmcnt(4): per iter {vmcnt(4); s_barrier; sched_barrier;
// stage(t+2); ds_read(t)+MFMA(t)} -- NO full drain in steady state. 4-way K-reduce
// via owner distribution (64KB, aliases buffers); epilogue on ALL 512 threads.
// K buffers use OWNER layout: u16x4 chunk per (tile, p, lane) -- K is private
// scratch read back only by later stage epilogues at the SAME positions, so the
// layout is free and turns 2B/32B-segment scalar ops into coalesced 8B/lane ops.
// XOR swizzle (involution on 16B chunks, source-side) keeps ds_read ~2-way (free).
// Grid XCD-swizzled: NP n-tiles per XCD share a weight slice (L2-resident).
template <int MODE, int STAGE, int NDIM, int KDIM>
__global__ __launch_bounds__(512, 2) void fused_gemm(GArgs a) {
  constexpr int BK = 128;
  constexpr int NITER = KDIM / BK;
  constexpr int NP = (NDIM / 64) / 8;

  extern __shared__ char smem_c[];  // 98304 = 3 x (A 16KB | B 16KB)

  const int tid = threadIdx.x;
  const int lane = tid & 63;
  const int wid = tid >> 6;
  const int kq = wid & 3;            // K-quarter (chunks kq*4..kq*4+3)
  const int nh = wid >> 2;           // N-half (32 cols)
  const int fr = lane & 15;
  const int kg = (lane >> 4) & 3;

  const int bid = blockIdx.x;
  const int nt = (bid & 7) * NP + ((bid >> 3) % NP);
  const int mt = (bid >> 3) / NP;
  const int brow = mt * 64, bcol = nt * 64;
  const int tile = mt * (NDIM / 64) + nt;   // stable across all M_STG dispatches

  // ---- staging geometry: per matrix 64 rows x 16 chunks(16B) = 1024 chunks;
  // thread covers q = tid (rows 0..31) and q = tid+512 (rows 32..63) at fixed
  // swizzled source chunk (cs^(r&7); r&7 invariant under +32). LDS dest linear.
  const int rs0 = tid >> 4;
  const int cgS = (tid & 15) ^ (rs0 & 7);
  const bf16* pA0 = a.A + (size_t)(brow + rs0) * KDIM + cgS * 8;
  const bf16* pA1 = pA0 + (size_t)32 * KDIM;
  const bf16* pB0 = a.Bt + (size_t)(bcol + rs0) * KDIM + cgS * 8;
  const bf16* pB1 = pB0 + (size_t)32 * KDIM;
  char* dA = smem_c + tid * 16;            // A region [0,16K) of each buffer
  char* dB = smem_c + 16384 + tid * 16;    // B region [16K,32K)

#define STAGE_TILE(T_)                                                       \
  {                                                                          \
    const int B_ = ((T_) % 3) * 32768;                                       \
    const int KO_ = (T_)*BK;                                                 \
    gload_lds16(pA0 + KO_, dA + B_); gload_lds16(pA1 + KO_, dA + B_ + 8192); \
    gload_lds16(pB0 + KO_, dB + B_); gload_lds16(pB1 + KO_, dB + B_ + 8192); \
  }

  // ---- ds_read bases: row r at byte r*256; chunk c = kq*4+kg, XOR (fr&7)=(r&7).
  const int xA = (((kq * 4 + kg) ^ (fr & 7)) << 4);
  const char* rA = smem_c + fr * 256 + xA;                      // + mf*4096 + buf
  const char* rB = smem_c + 16384 + (nh * 32 + fr) * 256 + xA;  // + nf*4096 + buf

  f32x4 acc[4][2] = {};   // [mf][nf'] this wave's K-quarter partial

  STAGE_TILE(0)
  STAGE_TILE(1)

#pragma unroll
  for (int t = 0; t < NITER; ++t) {
    if (t < NITER - 1) asm volatile("s_waitcnt vmcnt(4)" ::: "memory");
    else               asm volatile("s_waitcnt vmcnt(0)" ::: "memory");
    __builtin_amdgcn_s_barrier();
    __builtin_amdgcn_sched_barrier(0);
    if (t + 2 < NITER) STAGE_TILE(t + 2)
    const int BO = (t % 3) * 32768;
    short8 af[4], bw[2];
    af[0] = *(const short8*)(rA + BO);
    af[1] = *(const short8*)(rA + BO + 4096);
    af[2] = *(const short8*)(rA + BO + 8192);
    af[3] = *(const short8*)(rA + BO + 12288);
    bw[0] = *(const short8*)(rB + BO);
    bw[1] = *(const short8*)(rB + BO + 4096);
    __builtin_amdgcn_s_setprio(1);
#pragma unroll
    for (int mf = 0; mf < 4; ++mf)
#pragma unroll
      for (int nf = 0; nf < 2; ++nf) acc[mf][nf] = MFMA16(af[mf], bw[nf], acc[mf][nf]);
    __builtin_amdgcn_s_setprio(0);
  }
#undef STAGE_TILE

  // ---- 4-way K-reduce via owner distribution (aliases the staging buffers) ----
  // position p = mf*4 + nh*2 + nf (16 positions); slot byte = ((p*4+kq)<<10)+lane*16.
  __syncthreads();
#pragma unroll
  for (int mf = 0; mf < 4; ++mf)
#pragma unroll
    for (int nf = 0; nf < 2; ++nf)
      *(f32x4*)(smem_c + (((mf * 4 + nh * 2 + nf) * 4 + kq) << 10) + lane * 16) = acc[mf][nf];
  __syncthreads();

#pragma unroll
  for (int of = 0; of < 2; ++of) {
    const int p = wid * 2 + of;            // owned position
    const int mfo = p >> 2, nfo = p & 3;
    f32x4 s = {};
#pragma unroll
    for (int k = 0; k < 4; ++k)
      s += *(const f32x4*)(smem_c + (((p * 4 + k) << 10)) + lane * 16);

    // Epilogue (all 512 threads). C/D layout (m89): col=lane&15, row=(lane>>4)*4+e.
    const int c = bcol + nfo * 16 + fr;
    const int r0 = brow + mfo * 16 + kg * 4;
    if constexpr (MODE == M_PLAIN) {
#pragma unroll
      for (int e = 0; e < 4; ++e) a.Wout[(size_t)(r0 + e) * NDIM + c] = __float2bfloat16(s[e]);
    } else if constexpr (MODE == M_INIT) {
#pragma unroll
      for (int e = 0; e < 4; ++e) {
        const size_t idx = (size_t)(r0 + e) * NDIM + c;
        a.yW1[idx] = s[e];
        const float tv = tanh_fast(s[e] + a.b1[c]);
        a.T[idx] = __float2bfloat16(tv);
        a.G[idx] = CF[5][0] * tv;
      }
    } else if constexpr (MODE == M_STG) {
      // K owner-layout: chunk index = tile*1024 + p*64 + lane (u16x4 = 4 e-values)
      u16x4* Kq = (u16x4*)a.K;
      const size_t kbase = (size_t)tile * 1024 + (size_t)p * 64 + lane;
      const float bb = a.b2w1[c];
      float Kv[4], comb[4];
#pragma unroll
      for (int e = 0; e < 4; ++e) Kv[e] = s[e] + bb;
      if constexpr (STAGE <= 5) {
        u16x4 kw;
#pragma unroll
        for (int e = 0; e < 4; ++e) kw[e] = f2bf(Kv[e]);
        Kq[(size_t)(STAGE - 1) * KPLANE + kbase] = kw;   // coalesced 8B/lane
      }
#pragma unroll
      for (int e = 0; e < 4; ++e)
        comb[e] = a.yW1[(size_t)(r0 + e) * NDIM + c] + CF[STAGE - 1][STAGE - 1] * Kv[e];
      if constexpr (STAGE > 1 && CF[STAGE - 1][0] != 0.f) {
        u16x4 kj = Kq[0 * KPLANE + kbase];
#pragma unroll
        for (int e = 0; e < 4; ++e) comb[e] += CF[STAGE - 1][0] * bf2f(kj[e]);
      }
      if constexpr (STAGE > 2 && CF[STAGE - 1][1] != 0.f) {
        u16x4 kj = Kq[1 * KPLANE + kbase];
#pragma unroll
        for (int e = 0; e < 4; ++e) comb[e] += CF[STAGE - 1][1] * bf2f(kj[e]);
      }
      if constexpr (STAGE > 3 && CF[STAGE - 1][2] != 0.f) {
        u16x4 kj = Kq[2 * KPLANE + kbase];
#pragma unroll
        for (int e = 0; e < 4; ++e) comb[e] += CF[STAGE - 1][2] * bf2f(kj[e]);
      }
      if constexpr (STAGE > 4 && CF[STAGE - 1][3] != 0.f) {
        u16x4 kj = Kq[3 * KPLANE + kbase];
#pragma unroll
        for (int e = 0; e < 4; ++e) comb[e] += CF[STAGE - 1][3] * bf2f(kj[e]);
      }
      if constexpr (STAGE > 5 && CF[STAGE - 1][4] != 0.f) {
        u16x4 kj = Kq[4 * KPLANE + kbase];
#pragma unroll
        for (int e = 0; e < 4; ++e) comb[e] += CF[STAGE - 1][4] * bf2f(kj[e]);
      }
#pragma unroll
      for (int e = 0; e < 4; ++e) {
        const size_t idx = (size_t)(r0 + e) * NDIM + c;
        const float tv = tanh_fast(comb[e] + a.b1[c]);
        a.T[idx] = __float2bfloat16(tv);
        if constexpr (STAGE < 6) {
          if constexpr (CF[5][STAGE] != 0.f) a.G[idx] += CF[5][STAGE] * tv;
        } else {
          a.yW1[idx] = comb[e];              // 5th-order yW1 update
          a.G[idx] += CF[5][0] * tv;         // T_1-of-next-step contribution
        }
      }
    } else {  // M_FINAL
#pragma unroll
      for (int e = 0; e < 4; ++e) {
        const size_t idx = (size_t)(r0 + e) * NDIM + c;
        a.y[idx] = a.xin[idx] + s[e] + a.b2[c];
      }
    }
  }
}

// fp32 [R][C] -> bf16 [C][R]
__global__ void transpose_to_bf16(const float* __restrict__ in, bf16* __restrict__ out, int R,
                                  int C) {
  __shared__ float t[32][33];
  const int c0 = blockIdx.x * 32, r0 = blockIdx.y * 32;
#pragma unroll
  for (int i = threadIdx.y; i < 32; i += 8)
    t[i][threadIdx.x] = in[(size_t)(r0 + i) * C + c0 + threadIdx.x];
  __syncthreads();
#pragma unroll
  for (int i = threadIdx.y; i < 32; i += 8)
    out[(size_t)(c0 + i) * R + r0 + threadIdx.x] = __float2bfloat16(t[threadIdx.x][i]);
}

// fp32 -> bf16 elementwise (4 per thread)
__global__ void cast_bf16(const float* __restrict__ in, bf16* __restrict__ out, int n4) {
  int i = blockIdx.x * 256 + threadIdx.x;
  if (i < n4) {
    float4 v = *(const float4*)(in + i * 4);
    bf16* o = out + i * 4;
    o[0] = __float2bfloat16(v.x); o[1] = __float2bfloat16(v.y);
    o[2] = __float2bfloat16(v.z); o[3] = __float2bfloat16(v.w);
  }
}

// b2w1[h'] = sum_d b2[d] * W1[d][h']   (W1 f32 [1024][2048])
__global__ void b2w1_kernel(const float* __restrict__ b2, const float* __restrict__ W1,
                            float* __restrict__ out) {
  const int h = blockIdx.x * 256 + threadIdx.x;
  float s = 0.f;
  for (int d = 0; d < Ddim; ++d) s += b2[d] * W1[(size_t)d * Hdim + h];
  out[h] = s;
}

extern "C" void kernel_launch(void* const* d_in, const int* in_sizes, int n_in, void* d_out,
                              int out_size, void* d_ws, size_t ws_size, hipStream_t stream) {
  const float* x = (const float*)d_in[0];
  const float* W1 = (const float*)d_in[1];
  const float* b1 = (const float*)d_in[2];
  const float* W2 = (const float*)d_in[3];
  const float* b2 = (const float*)d_in[4];
  float* y = (float*)d_out;

  char* ws = (char*)d_ws;
  bf16* W1t = (bf16*)(ws + 0);                  // [2048][1024] bf16, 4 MB   (W1^T)
  bf16* W2bf = (bf16*)(ws + (4ull << 20));      // [2048][1024] bf16, 4 MB   (W2 rm)
  bf16* W2t = (bf16*)(ws + (8ull << 20));       // [1024][2048] bf16, 4 MB   (W2^T)
  bf16* W21t = (bf16*)(ws + (12ull << 20));     // [2048][2048] bf16, 8 MB   ((W2@W1)^T)
  bf16* xbf = (bf16*)(ws + (20ull << 20));      // [512][1024] bf16, 1 MB
  bf16* Tbuf = (bf16*)(ws + (21ull << 20));     // [512][2048] bf16, 2 MB
  bf16* Kbuf = (bf16*)(ws + (23ull << 20));     // 5 x MH bf16 (owner layout), 10 MB
  bf16* Gbf = (bf16*)(ws + (33ull << 20));      // [512][2048] bf16, 2 MB
  float* yW1 = (float*)(ws + (35ull << 20));    // [512][2048] f32, 4 MB
  float* Gacc = (float*)(ws + (39ull << 20));   // [512][2048] f32, 4 MB
  float* b2w1 = (float*)(ws + (43ull << 20));   // [2048] f32

  GArgs a = {};
  a.b1 = b1; a.b2w1 = b2w1; a.xin = x; a.b2 = b2;
  a.yW1 = yW1; a.T = Tbuf; a.K = Kbuf; a.G = Gacc; a.y = y;

  constexpr int SMEM = 98304;
  hipFuncSetAttribute((const void*)&fused_gemm<M_PLAIN, 0, Hdim, 1024>,
                      hipFuncAttributeMaxDynamicSharedMemorySize, SMEM);
  hipFuncSetAttribute((const void*)&fused_gemm<M_INIT, 0, Hdim, 1024>,
                      hipFuncAttributeMaxDynamicSharedMemorySize, SMEM);
  hipFuncSetAttribute((const void*)&fused_gemm<M_STG, 1, Hdim, Hdim>,
                      hipFuncAttributeMaxDynamicSharedMemorySize, SMEM);
  hipFuncSetAttribute((const void*)&fused_gemm<M_STG, 2, Hdim, Hdim>,
                      hipFuncAttributeMaxDynamicSharedMemorySize, SMEM);
  hipFuncSetAttribute((const void*)&fused_gemm<M_STG, 3, Hdim, Hdim>,
                      hipFuncAttributeMaxDynamicSharedMemorySize, SMEM);
  hipFuncSetAttribute((const void*)&fused_gemm<M_STG, 4, Hdim, Hdim>,
                      hipFuncAttributeMaxDynamicSharedMemorySize, SMEM);
  hipFuncSetAttribute((const void*)&fused_gemm<M_STG, 5, Hdim, Hdim>,
                      hipFuncAttributeMaxDynamicSharedMemorySize, SMEM);
  hipFuncSetAttribute((const void*)&fused_gemm<M_STG, 6, Hdim, Hdim>,
                      hipFuncAttributeMaxDynamicSharedMemorySize, SMEM);
  hipFuncSetAttribute((const void*)&fused_gemm<M_FINAL, 0, Ddim, Hdim>,
                      hipFuncAttributeMaxDynamicSharedMemorySize, SMEM);

  // ---- setup (one-time) ----
  transpose_to_bf16<<<dim3(Hdim / 32, Ddim / 32), dim3(32, 8), 0, stream>>>(W1, W1t, Ddim, Hdim);
  transpose_to_bf16<<<dim3(Ddim / 32, Hdim / 32), dim3(32, 8), 0, stream>>>(W2, W2t, Hdim, Ddim);
  cast_bf16<<<(Hdim * Ddim / 4 + 255) / 256, 256, 0, stream>>>(W2, W2bf, Hdim * Ddim / 4);
  cast_bf16<<<(Mdim * Ddim / 4 + 255) / 256, 256, 0, stream>>>(x, xbf, Mdim * Ddim / 4);
  b2w1_kernel<<<Hdim / 256, 256, 0, stream>>>(b2, W1, b2w1);

  // W21t[h'][h] = sum_d W1[d,h']*W2[h,d]  : A=W1t [2048][1024], Bt=W2bf [2048][1024]
  {
    GArgs p = a; p.A = W1t; p.Bt = W2bf; p.Wout = W21t;
    fused_gemm<M_PLAIN, 0, Hdim, 1024><<<32 * 32, 512, SMEM, stream>>>(p);
  }
  // init: yW1 = x@W1 ; T1 = tanh(yW1+b1) ; G = CF5[0]*tanh
  {
    GArgs p = a; p.A = xbf; p.Bt = W1t;
    fused_gemm<M_INIT, 0, Hdim, 1024><<<8 * 32, 512, SMEM, stream>>>(p);
  }

  // ---- 16 RK steps, one H-space GEMM per stage (skip last step's stage 6) ----
  GArgs sg = a; sg.A = Tbuf; sg.Bt = W21t;
  for (int step = 0; step < 16; ++step) {
    fused_gemm<M_STG, 1, Hdim, Hdim><<<8 * 32, 512, SMEM, stream>>>(sg);
    fused_gemm<M_STG, 2, Hdim, Hdim><<<8 * 32, 512, SMEM, stream>>>(sg);
    fused_gemm<M_STG, 3, Hdim, Hdim><<<8 * 32, 512, SMEM, stream>>>(sg);
    fused_gemm<M_STG, 4, Hdim, Hdim><<<8 * 32, 512, SMEM, stream>>>(sg);
    fused_gemm<M_STG, 5, Hdim, Hdim><<<8 * 32, 512, SMEM, stream>>>(sg);
    if (step < 15)
      fused_gemm<M_STG, 6, Hdim, Hdim><<<8 * 32, 512, SMEM, stream>>>(sg);
  }

  // ---- final: y = x + Gbf@W2 + b2 ----
  cast_bf16<<<(int)(MH / 4 + 255) / 256, 256, 0, stream>>>(Gacc, Gbf, (int)(MH / 4));
  {
    GArgs p = a; p.A = Gbf; p.Bt = W2t;
    fused_gemm<M_FINAL, 0, Ddim, Hdim><<<8 * 16, 512, SMEM, stream>>>(p);
  }
}

// Round 13
// 1357.516 us; speedup vs baseline: 2.2189x; 1.0164x over previous
//
#include <hip/hip_runtime.h>
#include <hip/hip_bf16.h>

using bf16 = __hip_bfloat16;
typedef __attribute__((ext_vector_type(8))) short short8;   // 8 bf16 (MFMA A/B frag)
typedef __attribute__((ext_vector_type(4))) float f32x4;
typedef __attribute__((ext_vector_type(16))) float f32x16;  // 32x32 MFMA C/D
typedef __attribute__((ext_vector_type(4))) unsigned short u16x4;  // 4 bf16 chunk

#define MFMA32(A, B, C) __builtin_amdgcn_mfma_f32_32x32x16_bf16(A, B, C, 0, 0, 0)

constexpr int Mdim = 512;
constexpr int Ddim = 1024;
constexpr int Hdim = 2048;
constexpr size_t MH = (size_t)Mdim * Hdim;   // 512*2048 (H-space activations)
constexpr size_t KPL4 = MH / 4;              // owner-layout u16x4/f32x4 chunks per plane

constexpr double Hs = 1.0 / 16.0;
// CF[s-1][j]: coefficient (times h) of K_{j+1} in the combination after stage s.
// Row 5 = 5th-order solution weights (also the G-accumulation weights).
constexpr float CF[6][6] = {
    {float(Hs * 1 / 5.), 0.f, 0.f, 0.f, 0.f, 0.f},
    {float(Hs * 3 / 40.), float(Hs * 9 / 40.), 0.f, 0.f, 0.f, 0.f},
    {float(Hs * 44 / 45.), float(-Hs * 56 / 15.), float(Hs * 32 / 9.), 0.f, 0.f, 0.f},
    {float(Hs * 19372 / 6561.), float(-Hs * 25360 / 2187.), float(Hs * 64448 / 6561.),
     float(-Hs * 212 / 729.), 0.f, 0.f},
    {float(Hs * 9017 / 3168.), float(-Hs * 355 / 33.), float(Hs * 46732 / 5247.),
     float(Hs * 49 / 176.), float(-Hs * 5103 / 18656.), 0.f},
    {float(Hs * 35 / 384.), 0.f, float(Hs * 500 / 1113.), float(Hs * 125 / 192.),
     float(-Hs * 2187 / 6784.), float(Hs * 11 / 84.)},
};

__device__ __forceinline__ float tanh_fast(float x) {
  float xc = fminf(fmaxf(x, -15.0f), 15.0f);
  float t = __expf(2.0f * xc);
  return (t - 1.0f) * __builtin_amdgcn_rcpf(t + 1.0f);
}

__device__ __forceinline__ unsigned short f2bf(float x) {
  bf16 b = __float2bfloat16(x);
  return *(unsigned short*)&b;
}
__device__ __forceinline__ float bf2f(unsigned short u) {
  bf16 b = *(bf16*)&u;
  return __bfloat162float(b);
}

__device__ __forceinline__ void gload_lds16(const void* g, void* lds) {
  __builtin_amdgcn_global_load_lds((const __attribute__((address_space(1))) void*)g,
                                   (__attribute__((address_space(3))) void*)lds, 16, 0, 0);
}

enum { M_PLAIN = 0, M_INIT = 1, M_STG = 2, M_FINAL = 3 };

struct GArgs {
  const bf16* A;      // [M][KDIM] bf16 row-major
  const bf16* Bt;     // [NDIM][KDIM] bf16 row-major (B transposed)
  const float* b1;    // bias for tanh input [NDIM]
  const float* b2w1;  // b2@W1 [2048]
  const float* xin;   // x f32 (FINAL)
  const float* b2;    // b2 (FINAL)
  float* yW1;         // MH f32, OWNER layout (f32x4 per (tile,q,lane))
  bf16* T;            // [512][2048] bf16 tanh output, row-major (next GEMM's A)
  bf16* K;            // 5 x MH bf16 K_j storage, OWNER layout (u16x4 chunks)
  float* G;           // [512][2048] f32 accumulated CF5-weighted tanh (row-major)
  bf16* Wout;         // PLAIN bf16 output (W21t)
  float* y;           // FINAL f32 output
};

// C = A(M x KDIM) * Bt^T; 64x64 block tile; 8 waves, EACH with the full 64x64 tile
// (2x2 frags of mfma_32x32x16_bf16) on a disjoint K=16 slice => every staged LDS
// byte is ds_read exactly ONCE (32KB reads + 32KB stage-writes per iter, vs 48+32
// for the old 4-way split). BK=128, THREE 32KB buffers, prefetch distance 2,
// counted vmcnt(4): {vmcnt(4); s_barrier; sched_barrier; stage(t+2); read+MFMA(t)}
// -- no full drain in steady state. 8-way K-reduce via 128KB LDS exchange (chunk
// q = frag*4+reg-group, 16 chunks x 8 waves x 1KB); owner (wid*2+of) sums 8 and
// runs the epilogue => all 512 threads active, 8 f32/thread.
// Owner layouts: yW1/K are internal scratch only touched at owner positions ->
// stored as (tile,q,lane) f32x4/u16x4 chunks, 1KB/wave single-instruction access.
// 32x32 C/D layout (m74/m101): col=lane&31, row=(reg&3)+8*(reg>>2)+4*(lane>>5).
// XOR swizzle (involution on 16B chunks, source-side) for ds_read bank spread.
// Grid XCD-swizzled: NP n-tiles per XCD share a weight slice (L2-resident).
template <int MODE, int STAGE, int NDIM, int KDIM>
__global__ __launch_bounds__(512, 2) void fused_gemm(GArgs a) {
  constexpr int BK = 128;
  constexpr int NITER = KDIM / BK;
  constexpr int NP = (NDIM / 64) / 8;

  extern __shared__ char smem_c[];  // 131072: staging 3x32KB; exchange 128KB after

  const int tid = threadIdx.x;
  const int lane = tid & 63;
  const int wid = tid >> 6;          // K-slice id (K=16 within BK=128)
  const int l31 = lane & 31;
  const int hi = lane >> 5;

  const int bid = blockIdx.x;
  const int nt = (bid & 7) * NP + ((bid >> 3) % NP);
  const int mt = (bid >> 3) / NP;
  const int brow = mt * 64, bcol = nt * 64;
  const int tile = mt * (NDIM / 64) + nt;   // stable across all dispatches

  // ---- staging: per matrix 64 rows x 16 chunks(16B) = 1024 chunks; thread covers
  // q = tid (rows 0..31) and q = tid+512 (rows 32..63) at fixed swizzled source
  // chunk (cs^(r&7); r&7 invariant under +32). LDS dest linear (gload constraint).
  const int rs0 = tid >> 4;
  const int cgS = (tid & 15) ^ (rs0 & 7);
  const bf16* pA0 = a.A + (size_t)(brow + rs0) * KDIM + cgS * 8;
  const bf16* pA1 = pA0 + (size_t)32 * KDIM;
  const bf16* pB0 = a.Bt + (size_t)(bcol + rs0) * KDIM + cgS * 8;
  const bf16* pB1 = pB0 + (size_t)32 * KDIM;
  char* dA = smem_c + tid * 16;            // A region [0,16K) of each buffer
  char* dB = smem_c + 16384 + tid * 16;    // B region [16K,32K)

#define STAGE_TILE(T_)                                                       \
  {                                                                          \
    const int B_ = ((T_) % 3) * 32768;                                       \
    const int KO_ = (T_)*BK;                                                 \
    gload_lds16(pA0 + KO_, dA + B_); gload_lds16(pA1 + KO_, dA + B_ + 8192); \
    gload_lds16(pB0 + KO_, dB + B_); gload_lds16(pB1 + KO_, dB + B_ + 8192); \
  }

  // ---- ds_read per-lane offset: row = mf*32 + l31 (A) / nf*32 + l31 (B), byte =
  // row*256 + chunk*16, chunk = (wid*2 + hi) ^ (row&7); row&7 == l31&7.
  const int xo = l31 * 256 + (((wid * 2 + hi) ^ (l31 & 7)) << 4);
  const char* rA = smem_c + xo;              // + mf*8192 + buf
  const char* rB = smem_c + 16384 + xo;      // + nf*8192 + buf

  f32x16 acc[2][2] = {};   // [mf][nf] 32x32 frags, this wave's K-slice partial

  STAGE_TILE(0)
  STAGE_TILE(1)

#pragma unroll
  for (int t = 0; t < NITER; ++t) {
    if (t < NITER - 1) asm volatile("s_waitcnt vmcnt(4)" ::: "memory");
    else               asm volatile("s_waitcnt vmcnt(0)" ::: "memory");
    __builtin_amdgcn_s_barrier();
    __builtin_amdgcn_sched_barrier(0);
    if (t + 2 < NITER) STAGE_TILE(t + 2)
    const int BO = (t % 3) * 32768;
    short8 af0 = *(const short8*)(rA + BO);
    short8 af1 = *(const short8*)(rA + BO + 8192);
    short8 bw0 = *(const short8*)(rB + BO);
    short8 bw1 = *(const short8*)(rB + BO + 8192);
    __builtin_amdgcn_s_setprio(1);
    acc[0][0] = MFMA32(af0, bw0, acc[0][0]);
    acc[0][1] = MFMA32(af0, bw1, acc[0][1]);
    acc[1][0] = MFMA32(af1, bw0, acc[1][0]);
    acc[1][1] = MFMA32(af1, bw1, acc[1][1]);
    __builtin_amdgcn_s_setprio(0);
  }
#undef STAGE_TILE

  // ---- 8-way K-reduce via owner distribution: chunk q = (mf*2+nf)*4 + g ----
  // slot byte = (q*8 + w)<<10 + lane*16 ; 16 chunks x 8 waves x 1KB = 128KB.
  __syncthreads();
#pragma unroll
  for (int mf = 0; mf < 2; ++mf)
#pragma unroll
    for (int nf = 0; nf < 2; ++nf)
#pragma unroll
      for (int g = 0; g < 4; ++g) {
        f32x4 v = {acc[mf][nf][g * 4 + 0], acc[mf][nf][g * 4 + 1],
                   acc[mf][nf][g * 4 + 2], acc[mf][nf][g * 4 + 3]};
        *(f32x4*)(smem_c + ((((mf * 2 + nf) * 4 + g) * 8 + wid) << 10) + lane * 16) = v;
      }
  __syncthreads();

#pragma unroll
  for (int of = 0; of < 2; ++of) {
    const int q = wid * 2 + of;        // owned chunk 0..15
    f32x4 s = {};
#pragma unroll
    for (int w = 0; w < 8; ++w)
      s += *(const f32x4*)(smem_c + (((q * 8 + w) << 10)) + lane * 16);

    // Epilogue (all 512 threads). q -> frag p=q>>2 (mf=p>>1, nf=p&1), reg-group g=q&3.
    const int p = q >> 2, g = q & 3;
    const int mf = p >> 1, nf = p & 1;
    const int c = bcol + nf * 32 + l31;
    const int r0 = brow + mf * 32 + g * 8 + hi * 4;   // rows r0..r0+3
    if constexpr (MODE == M_PLAIN) {
#pragma unroll
      for (int e = 0; e < 4; ++e) a.Wout[(size_t)(r0 + e) * NDIM + c] = __float2bfloat16(s[e]);
    } else if constexpr (MODE == M_INIT) {
      ((f32x4*)a.yW1)[(size_t)(tile * 16 + q) * 64 + lane] = s;
      const float bv = a.b1[c];
#pragma unroll
      for (int e = 0; e < 4; ++e) {
        const size_t idx = (size_t)(r0 + e) * NDIM + c;
        const float tv = tanh_fast(s[e] + bv);
        a.T[idx] = __float2bfloat16(tv);
        a.G[idx] = CF[5][0] * tv;
      }
    } else if constexpr (MODE == M_STG) {
      u16x4* Kq = (u16x4*)a.K;
      const size_t kb = (size_t)(tile * 16 + q) * 64 + lane;
      const float bb = a.b2w1[c];
      float Kv[4], comb[4];
      const f32x4 yv = ((const f32x4*)a.yW1)[kb];
#pragma unroll
      for (int e = 0; e < 4; ++e) Kv[e] = s[e] + bb;
      if constexpr (STAGE <= 5) {
        u16x4 kw;
#pragma unroll
        for (int e = 0; e < 4; ++e) kw[e] = f2bf(Kv[e]);
        Kq[(size_t)(STAGE - 1) * KPL4 + kb] = kw;     // coalesced 8B/lane
      }
#pragma unroll
      for (int e = 0; e < 4; ++e) comb[e] = yv[e] + CF[STAGE - 1][STAGE - 1] * Kv[e];
      if constexpr (STAGE > 1 && CF[STAGE - 1][0] != 0.f) {
        u16x4 kj = Kq[0 * KPL4 + kb];
#pragma unroll
        for (int e = 0; e < 4; ++e) comb[e] += CF[STAGE - 1][0] * bf2f(kj[e]);
      }
      if constexpr (STAGE > 2 && CF[STAGE - 1][1] != 0.f) {
        u16x4 kj = Kq[1 * KPL4 + kb];
#pragma unroll
        for (int e = 0; e < 4; ++e) comb[e] += CF[STAGE - 1][1] * bf2f(kj[e]);
      }
      if constexpr (STAGE > 3 && CF[STAGE - 1][2] != 0.f) {
        u16x4 kj = Kq[2 * KPL4 + kb];
#pragma unroll
        for (int e = 0; e < 4; ++e) comb[e] += CF[STAGE - 1][2] * bf2f(kj[e]);
      }
      if constexpr (STAGE > 4 && CF[STAGE - 1][3] != 0.f) {
        u16x4 kj = Kq[3 * KPL4 + kb];
#pragma unroll
        for (int e = 0; e < 4; ++e) comb[e] += CF[STAGE - 1][3] * bf2f(kj[e]);
      }
      if constexpr (STAGE > 5 && CF[STAGE - 1][4] != 0.f) {
        u16x4 kj = Kq[4 * KPL4 + kb];
#pragma unroll
        for (int e = 0; e < 4; ++e) comb[e] += CF[STAGE - 1][4] * bf2f(kj[e]);
      }
      if constexpr (STAGE == 6) {
        f32x4 cw = {comb[0], comb[1], comb[2], comb[3]};
        ((f32x4*)a.yW1)[kb] = cw;                     // 5th-order yW1 update
      }
      const float bv = a.b1[c];
#pragma unroll
      for (int e = 0; e < 4; ++e) {
        const size_t idx = (size_t)(r0 + e) * NDIM + c;
        const float tv = tanh_fast(comb[e] + bv);
        a.T[idx] = __float2bfloat16(tv);
        if constexpr (STAGE < 6) {
          if constexpr (CF[5][STAGE] != 0.f) a.G[idx] += CF[5][STAGE] * tv;
        } else {
          a.G[idx] += CF[5][0] * tv;                  // T_1-of-next-step contribution
        }
      }
    } else {  // M_FINAL
      const float bv = a.b2[c];
#pragma unroll
      for (int e = 0; e < 4; ++e) {
        const size_t idx = (size_t)(r0 + e) * NDIM + c;
        a.y[idx] = a.xin[idx] + s[e] + bv;
      }
    }
  }
}

// fp32 [R][C] -> bf16 [C][R]
__global__ void transpose_to_bf16(const float* __restrict__ in, bf16* __restrict__ out, int R,
                                  int C) {
  __shared__ float t[32][33];
  const int c0 = blockIdx.x * 32, r0 = blockIdx.y * 32;
#pragma unroll
  for (int i = threadIdx.y; i < 32; i += 8)
    t[i][threadIdx.x] = in[(size_t)(r0 + i) * C + c0 + threadIdx.x];
  __syncthreads();
#pragma unroll
  for (int i = threadIdx.y; i < 32; i += 8)
    out[(size_t)(c0 + i) * R + r0 + threadIdx.x] = __float2bfloat16(t[threadIdx.x][i]);
}

// fp32 -> bf16 elementwise (4 per thread)
__global__ void cast_bf16(const float* __restrict__ in, bf16* __restrict__ out, int n4) {
  int i = blockIdx.x * 256 + threadIdx.x;
  if (i < n4) {
    float4 v = *(const float4*)(in + i * 4);
    bf16* o = out + i * 4;
    o[0] = __float2bfloat16(v.x); o[1] = __float2bfloat16(v.y);
    o[2] = __float2bfloat16(v.z); o[3] = __float2bfloat16(v.w);
  }
}

// b2w1[h'] = sum_d b2[d] * W1[d][h']   (W1 f32 [1024][2048])
__global__ void b2w1_kernel(const float* __restrict__ b2, const float* __restrict__ W1,
                            float* __restrict__ out) {
  const int h = blockIdx.x * 256 + threadIdx.x;
  float s = 0.f;
  for (int d = 0; d < Ddim; ++d) s += b2[d] * W1[(size_t)d * Hdim + h];
  out[h] = s;
}

extern "C" void kernel_launch(void* const* d_in, const int* in_sizes, int n_in, void* d_out,
                              int out_size, void* d_ws, size_t ws_size, hipStream_t stream) {
  const float* x = (const float*)d_in[0];
  const float* W1 = (const float*)d_in[1];
  const float* b1 = (const float*)d_in[2];
  const float* W2 = (const float*)d_in[3];
  const float* b2 = (const float*)d_in[4];
  float* y = (float*)d_out;

  char* ws = (char*)d_ws;
  bf16* W1t = (bf16*)(ws + 0);                  // [2048][1024] bf16, 4 MB   (W1^T)
  bf16* W2bf = (bf16*)(ws + (4ull << 20));      // [2048][1024] bf16, 4 MB   (W2 rm)
  bf16* W2t = (bf16*)(ws + (8ull << 20));       // [1024][2048] bf16, 4 MB   (W2^T)
  bf16* W21t = (bf16*)(ws + (12ull << 20));     // [2048][2048] bf16, 8 MB   ((W2@W1)^T)
  bf16* xbf = (bf16*)(ws + (20ull << 20));      // [512][1024] bf16, 1 MB
  bf16* Tbuf = (bf16*)(ws + (21ull << 20));     // [512][2048] bf16, 2 MB
  bf16* Kbuf = (bf16*)(ws + (23ull << 20));     // 5 x MH bf16 (owner layout), 10 MB
  bf16* Gbf = (bf16*)(ws + (33ull << 20));      // [512][2048] bf16, 2 MB
  float* yW1 = (float*)(ws + (35ull << 20));    // MH f32 (owner layout), 4 MB
  float* Gacc = (float*)(ws + (39ull << 20));   // [512][2048] f32, 4 MB
  float* b2w1 = (float*)(ws + (43ull << 20));   // [2048] f32

  GArgs a = {};
  a.b1 = b1; a.b2w1 = b2w1; a.xin = x; a.b2 = b2;
  a.yW1 = yW1; a.T = Tbuf; a.K = Kbuf; a.G = Gacc; a.y = y;

  constexpr int SMEM = 131072;
  hipFuncSetAttribute((const void*)&fused_gemm<M_PLAIN, 0, Hdim, 1024>,
                      hipFuncAttributeMaxDynamicSharedMemorySize, SMEM);
  hipFuncSetAttribute((const void*)&fused_gemm<M_INIT, 0, Hdim, 1024>,
                      hipFuncAttributeMaxDynamicSharedMemorySize, SMEM);
  hipFuncSetAttribute((const void*)&fused_gemm<M_STG, 1, Hdim, Hdim>,
                      hipFuncAttributeMaxDynamicSharedMemorySize, SMEM);
  hipFuncSetAttribute((const void*)&fused_gemm<M_STG, 2, Hdim, Hdim>,
                      hipFuncAttributeMaxDynamicSharedMemorySize, SMEM);
  hipFuncSetAttribute((const void*)&fused_gemm<M_STG, 3, Hdim, Hdim>,
                      hipFuncAttributeMaxDynamicSharedMemorySize, SMEM);
  hipFuncSetAttribute((const void*)&fused_gemm<M_STG, 4, Hdim, Hdim>,
                      hipFuncAttributeMaxDynamicSharedMemorySize, SMEM);
  hipFuncSetAttribute((const void*)&fused_gemm<M_STG, 5, Hdim, Hdim>,
                      hipFuncAttributeMaxDynamicSharedMemorySize, SMEM);
  hipFuncSetAttribute((const void*)&fused_gemm<M_STG, 6, Hdim, Hdim>,
                      hipFuncAttributeMaxDynamicSharedMemorySize, SMEM);
  hipFuncSetAttribute((const void*)&fused_gemm<M_FINAL, 0, Ddim, Hdim>,
                      hipFuncAttributeMaxDynamicSharedMemorySize, SMEM);

  // ---- setup (one-time) ----
  transpose_to_bf16<<<dim3(Hdim / 32, Ddim / 32), dim3(32, 8), 0, stream>>>(W1, W1t, Ddim, Hdim);
  transpose_to_bf16<<<dim3(Ddim / 32, Hdim / 32), dim3(32, 8), 0, stream>>>(W2, W2t, Hdim, Ddim);
  cast_bf16<<<(Hdim * Ddim / 4 + 255) / 256, 256, 0, stream>>>(W2, W2bf, Hdim * Ddim / 4);
  cast_bf16<<<(Mdim * Ddim / 4 + 255) / 256, 256, 0, stream>>>(x, xbf, Mdim * Ddim / 4);
  b2w1_kernel<<<Hdim / 256, 256, 0, stream>>>(b2, W1, b2w1);

  // W21t[h'][h] = sum_d W1[d,h']*W2[h,d]  : A=W1t [2048][1024], Bt=W2bf [2048][1024]
  {
    GArgs p = a; p.A = W1t; p.Bt = W2bf; p.Wout = W21t;
    fused_gemm<M_PLAIN, 0, Hdim, 1024><<<32 * 32, 512, SMEM, stream>>>(p);
  }
  // init: yW1 = x@W1 (owner layout) ; T1 = tanh(+b1) ; G = CF5[0]*tanh
  {
    GArgs p = a; p.A = xbf; p.Bt = W1t;
    fused_gemm<M_INIT, 0, Hdim, 1024><<<8 * 32, 512, SMEM, stream>>>(p);
  }

  // ---- 16 RK steps, one H-space GEMM per stage (skip last step's stage 6) ----
  GArgs sg = a; sg.A = Tbuf; sg.Bt = W21t;
  for (int step = 0; step < 16; ++step) {
    fused_gemm<M_STG, 1, Hdim, Hdim><<<8 * 32, 512, SMEM, stream>>>(sg);
    fused_gemm<M_STG, 2, Hdim, Hdim><<<8 * 32, 512, SMEM, stream>>>(sg);
    fused_gemm<M_STG, 3, Hdim, Hdim><<<8 * 32, 512, SMEM, stream>>>(sg);
    fused_gemm<M_STG, 4, Hdim, Hdim><<<8 * 32, 512, SMEM, stream>>>(sg);
    fused_gemm<M_STG, 5, Hdim, Hdim><<<8 * 32, 512, SMEM, stream>>>(sg);
    if (step < 15)
      fused_gemm<M_STG, 6, Hdim, Hdim><<<8 * 32, 512, SMEM, stream>>>(sg);
  }

  // ---- final: y = x + Gbf@W2 + b2 ----
  cast_bf16<<<(int)(MH / 4 + 255) / 256, 256, 0, stream>>>(Gacc, Gbf, (int)(MH / 4));
  {
    GArgs p = a; p.A = Gbf; p.Bt = W2t;
    fused_gemm<M_FINAL, 0, Ddim, Hdim><<<8 * 16, 512, SMEM, stream>>>(p);
  }
}